// Round 2
// baseline (809.818 us; speedup 1.0000x reference)
//
#include <hip/hip_runtime.h>
#include <hip/hip_bf16.h>

// Problem constants
#define KCODES 2048
#define DIM 256
#define TLEN 2048
#define NB 16
#define NROWS (NB * TLEN)          // 32768 rows (b*t)
#define NELEM (NB * DIM * TLEN)    // 8388608 elements of x / quant
#define LOSS_OFF NELEM
#define IDX_OFF (NELEM + 2)

// Approx filter margin (R8 analysis: requirement is s(n*) - min_n s(n) <= MARGIN,
// ~50-sigma safety for the single bf16 hi*hi sweep; unchanged by the running-min
// candidate scheme since any running min >= final min).
#define MARGIN 3e-3f

// Candidate list capacity per row (E[#cands] ~ 13 with cross-wave shared running
// min; overflow handled exactly by full-scan fallback in recheck).
#define CCAP 48

// ws layout (bytes) — total ~8.0 MB
#define OFF_XSQ   0ull                       // 131072
#define OFF_ESQ   131072ull                  // 8192
#define OFF_KEYS  139264ull                  // 262144
#define OFF_BSUM  401408ull                  // 131072
#define OFF_EHI   532480ull                  // 1048576
#define OFF_CCNT  1581056ull                 // 131072
#define OFF_CLIST 1712128ull                 // 32768*48*4 = 6291456
#define WS_NEED   8003584ull

typedef __bf16 bf16x8 __attribute__((ext_vector_type(8)));
typedef float  f32x4  __attribute__((ext_vector_type(4)));

__device__ __forceinline__ float sq_rn(float v) { return __fmul_rn(v, v); }

// order-preserving float<->u32 encoding for atomicMin on possibly-negative floats
__device__ __forceinline__ unsigned encf(float f) {
    unsigned u = __float_as_uint(f);
    return (u & 0x80000000u) ? ~u : (u | 0x80000000u);
}
__device__ __forceinline__ float decf(unsigned k) {
    return __uint_as_float((k & 0x80000000u) ? (k & 0x7FFFFFFFu) : ~k);
}

// ---- x_sq: numpy pairwise sum (8-acc/128-block) — bit-exact vs np
__global__ __launch_bounds__(256) void xsq_kernel(const float* __restrict__ x,
                                                  float* __restrict__ xsq) {
    int m = blockIdx.x * 256 + threadIdx.x;
    int b = m >> 11, t = m & (TLEN - 1);
    const float* p = x + (size_t)b * DIM * TLEN + t;
    float h[2];
#pragma unroll
    for (int half = 0; half < 2; ++half) {
        int c0 = half * 128;
        float r[8];
#pragma unroll
        for (int j = 0; j < 8; ++j) r[j] = sq_rn(p[(size_t)(c0 + j) * TLEN]);
        for (int i = 8; i < 128; i += 8) {
#pragma unroll
            for (int j = 0; j < 8; ++j)
                r[j] = __fadd_rn(r[j], sq_rn(p[(size_t)(c0 + i + j) * TLEN]));
        }
        h[half] = __fadd_rn(__fadd_rn(__fadd_rn(r[0], r[1]), __fadd_rn(r[2], r[3])),
                            __fadd_rn(__fadd_rn(r[4], r[5]), __fadd_rn(r[6], r[7])));
    }
    xsq[m] = __fadd_rn(h[0], h[1]);
}

__global__ __launch_bounds__(256) void esq_kernel(const float* __restrict__ cb,
                                                  float* __restrict__ esq) {
    int k = blockIdx.x * 256 + threadIdx.x;
    const float* p = cb + (size_t)k * DIM;
    float h[2];
#pragma unroll
    for (int half = 0; half < 2; ++half) {
        int c0 = half * 128;
        float r[8];
#pragma unroll
        for (int j = 0; j < 8; ++j) r[j] = sq_rn(p[c0 + j]);
        for (int i = 8; i < 128; i += 8) {
#pragma unroll
            for (int j = 0; j < 8; ++j)
                r[j] = __fadd_rn(r[j], sq_rn(p[c0 + i + j]));
        }
        h[half] = __fadd_rn(__fadd_rn(__fadd_rn(r[0], r[1]), __fadd_rn(r[2], r[3])),
                            __fadd_rn(__fadd_rn(r[4], r[5]), __fadd_rn(r[6], r[7])));
    }
    esq[k] = __fadd_rn(h[0], h[1]);
}

// ---- codebook [n][k] fp32 -> Ehi [n][k] bf16
__global__ __launch_bounds__(256) void split_e_kernel(const float* __restrict__ cb,
                                                      __hip_bfloat16* __restrict__ Ehi) {
    int i4 = (blockIdx.x * 256 + threadIdx.x) << 2;
    float4 v = *reinterpret_cast<const float4*>(cb + i4);
    alignas(8) __hip_bfloat16 h4[4];
    h4[0] = __float2bfloat16(v.x); h4[1] = __float2bfloat16(v.y);
    h4[2] = __float2bfloat16(v.z); h4[3] = __float2bfloat16(v.w);
    *reinterpret_cast<int2*>(Ehi + i4) = *reinterpret_cast<int2*>(h4);
}

// ---- stage one [128 codes][64 k] bf16 chunk of Ehi into LDS via global_load_lds,
// with the R1-proven pre-swizzled-source XOR pattern (read side XORs (c&7)<<4).
__device__ __forceinline__ void stage_chunk(const __hip_bfloat16* __restrict__ Ehi,
                                            __hip_bfloat16* dstbase,
                                            int s, int w, int srow, int scol) {
    int nt = s >> 2, kc = (s & 3) << 6;
    const __hip_bfloat16* gsrc =
        Ehi + (size_t)((nt << 7) + (w << 5) + srow) * DIM + kc + scol;
#pragma unroll
    for (int j = 0; j < 4; ++j)
        __builtin_amdgcn_global_load_lds(
            (const __attribute__((address_space(1))) unsigned int*)(gsrc + (size_t)(j << 3) * DIM),
            (__attribute__((address_space(3))) unsigned int*)(dstbase + (((w << 5) + (j << 3)) << 6)),
            16, 0, 0);
}

// ---- Phase A (restructured): 64 rows/block, loop over ALL 2048 codes.
// A-frags (x rows, full K) loaded once from x (fp32->bf16, same rounding as the
// old split_x -> identical products). Ehi streamed through a 3-buffer LDS ring
// with counted vmcnt(4) + raw s_barrier (1 barrier/chunk, prefetch depth 2).
// Output: per-row compact candidate lists (running-min + MARGIN filter).
__global__ __launch_bounds__(256, 2) void dist_cand_kernel(const float* __restrict__ x,
                                                           const __hip_bfloat16* __restrict__ Ehi,
                                                           const float* __restrict__ esq,
                                                           int* __restrict__ ccnt_g,
                                                           int* __restrict__ clist_g) {
    __shared__ __hip_bfloat16 Bh[3][128 * 64];   // 48 KB, swizzled code tiles
    __shared__ float esq_s[KCODES];              // 8 KB
    __shared__ int clist_s[64][CCAP];            // 12 KB
    __shared__ int ccnt_s[64];
    __shared__ unsigned rmin_s[64];

    int tid = threadIdx.x;
    int w = tid >> 6, lane = tid & 63;
    int q = lane >> 4, c = lane & 15;
    int swzc = (c & 7) << 4;
    int blk = blockIdx.x;                         // 512 blocks, 64 rows each
    int b = blk >> 5;
    int t0 = (blk << 6) & (TLEN - 1);
    const float* xb = x + (size_t)b * DIM * TLEN + t0;

    // esq -> LDS (epilogue reads become lgkm-only; keeps loop vmcnt clean)
#pragma unroll
    for (int i = 0; i < 8; ++i) esq_s[tid + i * 256] = esq[tid + i * 256];
    if (tid < 64) { ccnt_s[tid] = 0; rmin_s[tid] = 0xFF7FFFFFu; }  // enc(+3.4e38)

    // A-frags: xf[mi][kh]: row t0 + mi*16 + c, k = kh*32 + q*8 + j
    bf16x8 xf[4][8];
#pragma unroll
    for (int mi = 0; mi < 4; ++mi) {
        int t = (mi << 4) + c;
#pragma unroll
        for (int kh = 0; kh < 8; ++kh) {
            alignas(16) __hip_bfloat16 h8[8];
#pragma unroll
            for (int j = 0; j < 8; ++j)
                h8[j] = __float2bfloat16(xb[(size_t)((kh << 5) + (q << 3) + j) * TLEN + t]);
            xf[mi][kh] = *reinterpret_cast<bf16x8*>(h8);
        }
    }

    f32x4 acc[2][4];
#pragma unroll
    for (int ci = 0; ci < 2; ++ci)
#pragma unroll
        for (int mi = 0; mi < 4; ++mi) acc[ci][mi] = (f32x4){0.f, 0.f, 0.f, 0.f};

    int srow = lane >> 3;
    int scol = ((lane & 7) ^ srow) << 3;

    // full drain (vmcnt(0) lgkm(0)) + barrier: A-loads + LDS inits settled,
    // so in-loop vmcnt counts ONLY stage loads (4 per thread per chunk).
    __syncthreads();

    stage_chunk(Ehi, &Bh[0][0], 0, w, srow, scol);
    stage_chunk(Ehi, &Bh[1][0], 1, w, srow, scol);

    int cur = 0, stb = 2;
#pragma unroll 1
    for (int nt = 0; nt < 16; ++nt) {
#pragma unroll
        for (int kc = 0; kc < 4; ++kc) {
            // wait for chunk s (2 chunks in flight behind it), then barrier.
            if (kc == 3) {
                if (nt == 15) asm volatile("s_waitcnt vmcnt(0)\n\ts_barrier" ::: "memory");
                else          asm volatile("s_waitcnt vmcnt(4)\n\ts_barrier" ::: "memory");
            } else {
                asm volatile("s_waitcnt vmcnt(4)\n\ts_barrier" ::: "memory");
            }
            // prefetch chunk s+2 into the buffer chunk s-1 just finished with
            int s2 = (nt << 2) + kc + 2;
            if (s2 < 64) stage_chunk(Ehi, &Bh[stb][0], s2, w, srow, scol);

            const char* basep = reinterpret_cast<const char*>(&Bh[cur][0]);
#pragma unroll
            for (int kh = 0; kh < 2; ++kh) {
                int swz = ((kh << 6) | (q << 4)) ^ swzc;
                bf16x8 cf0 = *reinterpret_cast<const bf16x8*>(basep + ((((w << 5) + c) << 7) + swz));
                bf16x8 cf1 = *reinterpret_cast<const bf16x8*>(basep + ((((w << 5) + 16 + c) << 7) + swz));
#pragma unroll
                for (int mi = 0; mi < 4; ++mi) {
                    acc[0][mi] = __builtin_amdgcn_mfma_f32_16x16x32_bf16(cf0, xf[mi][(kc << 1) | kh], acc[0][mi], 0, 0, 0);
                    acc[1][mi] = __builtin_amdgcn_mfma_f32_16x16x32_bf16(cf1, xf[mi][(kc << 1) | kh], acc[1][mi], 0, 0, 0);
                }
            }
            int oc = cur; cur = (cur == 2) ? 0 : cur + 1; stb = oc;
        }

        // per-nt epilogue: s = esq - 2*acc (= approx d2 - xsq, row-constant shift
        // cancels in all comparisons). Running min + margin -> candidate appends.
        float ev[8];
#pragma unroll
        for (int ci = 0; ci < 2; ++ci)
#pragma unroll
            for (int reg = 0; reg < 4; ++reg)
                ev[ci * 4 + reg] = esq_s[(nt << 7) + (w << 5) + (ci << 4) + (q << 2) + reg];

#pragma unroll
        for (int mi = 0; mi < 4; ++mi) {
            int r = (mi << 4) + c;
            float s8[8];
#pragma unroll
            for (int ci = 0; ci < 2; ++ci)
#pragma unroll
                for (int reg = 0; reg < 4; ++reg)
                    s8[ci * 4 + reg] = fmaf(-2.0f, acc[ci][mi][reg], ev[ci * 4 + reg]);
            float t01 = fminf(fminf(s8[0], s8[1]), fminf(s8[2], s8[3]));
            float t23 = fminf(fminf(s8[4], s8[5]), fminf(s8[6], s8[7]));
            float tmin = fminf(t01, t23);
            tmin = fminf(tmin, __shfl_xor(tmin, 16, 64));
            tmin = fminf(tmin, __shfl_xor(tmin, 32, 64));
            float shf = decf(rmin_s[r]);
            float thr = fminf(tmin, shf) + MARGIN;
#pragma unroll
            for (int v = 0; v < 8; ++v) {
                if (s8[v] <= thr) {
                    int n = (nt << 7) + (w << 5) + ((v >> 2) << 4) + (q << 2) + (v & 3);
                    int pos = atomicAdd(&ccnt_s[r], 1);
                    if (pos < CCAP) clist_s[r][pos] = n;
                }
            }
            if (q == 0) atomicMin(&rmin_s[r], encf(tmin));
            // reset accumulators for next nt
#pragma unroll
            for (int ci = 0; ci < 2; ++ci) acc[ci][mi] = (f32x4){0.f, 0.f, 0.f, 0.f};
        }
    }

    __syncthreads();
    {
        int r = tid >> 2, jj = tid & 3;
        int cnt = ccnt_s[r];
        int m = (blk << 6) + r;
        if (jj == 0) ccnt_g[m] = cnt;               // raw count (overflow detect)
        int cl = cnt > CCAP ? CCAP : cnt;
        for (int j = jj; j < cl; j += 4)
            clist_g[(size_t)m * CCAP + j] = clist_s[r][j];
    }
}

// ---- Phase B: exact recheck over candidate lists. Full-scan fallback on
// overflow guarantees exactness unconditionally. Final d2 uses the exact ref
// rounding chain; min over (d2, n) with lower-n tie-break (order-independent).
__global__ __launch_bounds__(256) void recheck_kernel(const float* __restrict__ x,
                                                      const float* __restrict__ cb,
                                                      const float* __restrict__ xsq,
                                                      const float* __restrict__ esq,
                                                      const int* __restrict__ ccnt,
                                                      const int* __restrict__ clist,
                                                      unsigned long long* __restrict__ keys) {
    __shared__ float xT[DIM * 33];

    int tid = threadIdx.x;
    int blk = blockIdx.x;               // 1024 blocks, 32 rows each
    int b = blk >> 6, t0 = (blk & 63) << 5;
    const float* xb = x + (size_t)b * DIM * TLEN + t0;

    {   // coalesced staging: 8 c-rows x 32 t per iter
        int tl = tid & 31, c8 = tid >> 5;
        for (int cc = 0; cc < 32; ++cc) {
            int c = (cc << 3) + c8;
            xT[c * 33 + tl] = xb[(size_t)c * TLEN + tl];
        }
    }
    __syncthreads();

    int g = tid >> 3, l3 = tid & 7;     // group g handles row t0+g
    int m = (b << 11) + t0 + g;
    int cnt = ccnt[m];
    float xs = xsq[m];
    float bd = 3.4e38f; int bi = 0x7fffffff;

    if (cnt <= CCAP) {
        for (int j = l3; j < cnt; j += 8) {
            int n = clist[(size_t)m * CCAP + j];
            const float* crow = cb + (size_t)n * DIM;
            float d = 0.f;
            for (int k = 0; k < DIM; k += 4) {     // ascending-k fmaf chain == np mm
                float4 cv = *reinterpret_cast<const float4*>(crow + k);
                d = fmaf(xT[(k + 0) * 33 + g], cv.x, d);
                d = fmaf(xT[(k + 1) * 33 + g], cv.y, d);
                d = fmaf(xT[(k + 2) * 33 + g], cv.z, d);
                d = fmaf(xT[(k + 3) * 33 + g], cv.w, d);
            }
            float d2 = __fadd_rn(__fadd_rn(xs, -2.0f * d), esq[n]);
            if (d2 < bd || (d2 == bd && n < bi)) { bd = d2; bi = n; }
        }
    } else {
        // overflow fallback: exact full scan (same formula, any order is fine)
        for (int n = l3; n < KCODES; n += 8) {
            const float* crow = cb + (size_t)n * DIM;
            float d = 0.f;
            for (int k = 0; k < DIM; k += 4) {
                float4 cv = *reinterpret_cast<const float4*>(crow + k);
                d = fmaf(xT[(k + 0) * 33 + g], cv.x, d);
                d = fmaf(xT[(k + 1) * 33 + g], cv.y, d);
                d = fmaf(xT[(k + 2) * 33 + g], cv.z, d);
                d = fmaf(xT[(k + 3) * 33 + g], cv.w, d);
            }
            float d2 = __fadd_rn(__fadd_rn(xs, -2.0f * d), esq[n]);
            if (d2 < bd || (d2 == bd && n < bi)) { bd = d2; bi = n; }
        }
    }
    for (int off = 1; off < 8; off <<= 1) {
        float od = __shfl_xor(bd, off, 8);
        int   oi = __shfl_xor(bi, off, 8);
        if (od < bd || (od == bd && oi < bi)) { bd = od; bi = oi; }
    }
    if (l3 == 0)
        keys[m] = ((unsigned long long)__float_as_uint(bd) << 32) | (unsigned)(bi & 2047);
}

// ======== fallback path (R5): used only if ws_size is too small ========
__global__ __launch_bounds__(256) void init_keys_kernel(unsigned long long* __restrict__ keys) {
    keys[blockIdx.x * 256 + threadIdx.x] = ~0ULL;
}

__global__ __launch_bounds__(256, 4) void dist_kernel(const float* __restrict__ x,
                                                      const float* __restrict__ cb,
                                                      const float* __restrict__ xsq,
                                                      const float* __restrict__ esq,
                                                      unsigned long long* __restrict__ keys) {
    __shared__ float As[16][128];
    __shared__ float Bs[16][132];
    int blk = blockIdx.x;
    int nt = blk & 15, mt = blk >> 4;
    int m0 = mt << 7;
    int b = m0 >> 11, t0 = m0 & (TLEN - 1);
    int n0 = nt << 7;
    int tid = threadIdx.x;
    int tm = tid >> 4, tn = tid & 15;
    const float* xbase = x + (size_t)b * DIM * TLEN + t0;
    float acc[8][8] = {};
    for (int kk = 0; kk < DIM; kk += 16) {
#pragma unroll
        for (int h = 0; h < 2; ++h) {
            int qq = tid + (h << 8);
            int k = qq >> 5, mq = (qq & 31) << 2;
            float4 v = *reinterpret_cast<const float4*>(xbase + (size_t)(kk + k) * TLEN + mq);
            *reinterpret_cast<float4*>(&As[k][mq]) = v;
        }
#pragma unroll
        for (int h = 0; h < 2; ++h) {
            int qq = tid + (h << 8);
            int nr = qq >> 2, kc = (qq & 3) << 2;
            float4 v = *reinterpret_cast<const float4*>(cb + (size_t)(n0 + nr) * DIM + kk + kc);
            Bs[kc + 0][nr] = v.x; Bs[kc + 1][nr] = v.y;
            Bs[kc + 2][nr] = v.z; Bs[kc + 3][nr] = v.w;
        }
        __syncthreads();
#pragma unroll
        for (int k = 0; k < 16; ++k) {
            float4 a0 = *reinterpret_cast<const float4*>(&As[k][tm << 2]);
            float4 a1 = *reinterpret_cast<const float4*>(&As[k][64 + (tm << 2)]);
            float4 b0 = *reinterpret_cast<const float4*>(&Bs[k][tn << 2]);
            float4 b1 = *reinterpret_cast<const float4*>(&Bs[k][64 + (tn << 2)]);
            float am[8] = {a0.x, a0.y, a0.z, a0.w, a1.x, a1.y, a1.z, a1.w};
            float bn[8] = {b0.x, b0.y, b0.z, b0.w, b1.x, b1.y, b1.z, b1.w};
#pragma unroll
            for (int mi = 0; mi < 8; ++mi)
#pragma unroll
                for (int ni = 0; ni < 8; ++ni)
                    acc[mi][ni] = fmaf(am[mi], bn[ni], acc[mi][ni]);
        }
        __syncthreads();
    }
    int cn[8]; float es[8];
#pragma unroll
    for (int ni = 0; ni < 8; ++ni) {
        cn[ni] = n0 + ((ni < 4) ? (tn << 2) + ni : 60 + (tn << 2) + ni);
        es[ni] = esq[cn[ni]];
    }
#pragma unroll
    for (int mi = 0; mi < 8; ++mi) {
        int m = m0 + ((mi < 4) ? (tm << 2) + mi : 60 + (tm << 2) + mi);
        float xs = xsq[m];
        float bd = 3.4e38f;
        int bi = 0x7fffffff;
#pragma unroll
        for (int ni = 0; ni < 8; ++ni) {
            float d2 = __fadd_rn(__fadd_rn(xs, -2.0f * acc[mi][ni]), es[ni]);
            if (d2 < bd) { bd = d2; bi = cn[ni]; }
        }
        for (int off = 1; off < 16; off <<= 1) {
            float od = __shfl_xor(bd, off, 16);
            int oi = __shfl_xor(bi, off, 16);
            if (od < bd || (od == bd && oi < bi)) { bd = od; bi = oi; }
        }
        if (tn == 0) {
            unsigned long long key =
                ((unsigned long long)__float_as_uint(bd) << 32) | (unsigned)(bi & 2047);
            atomicMin(&keys[m], key);
        }
    }
}
// ======== end fallback ========

// ---- gather + STE output + idx + per-block loss sums.
// Reblocked to c-quads: one float4 cb read per 4 output elements (4x less L2
// line traffic from the scattered gather). bsum groups (b, c, t/256) and their
// shfl-tree order are reproduced exactly -> loss bit-identical.
__global__ __launch_bounds__(256) void gather_kernel(const float* __restrict__ x,
                                                     const float* __restrict__ cb,
                                                     const unsigned long long* __restrict__ keys,
                                                     float* __restrict__ out,
                                                     float* __restrict__ bsum) {
    int tid = threadIdx.x;
    int blk = blockIdx.x;               // 8192 = 16 b x 8 tc x 64 c4
    int c4 = blk & 63, tc = (blk >> 6) & 7, b = blk >> 9;
    int c0 = c4 << 2;
    int t = (tc << 8) + tid;
    int m = (b << 11) + t;
    unsigned idx = (unsigned)(keys[m]) & 2047u;
    float4 cv = *reinterpret_cast<const float4*>(cb + (size_t)idx * DIM + c0);
    if (c4 == 0) out[(size_t)IDX_OFF + m] = (float)idx;

    float qv[4] = {cv.x, cv.y, cv.z, cv.w};
    __shared__ float wsum[4][4];
    int lane = tid & 63, wid = tid >> 6;
    float sv[4];
#pragma unroll
    for (int cc = 0; cc < 4; ++cc) {
        size_t e = (size_t)b * (DIM * TLEN) + (size_t)(c0 + cc) * TLEN + t;
        float xv = x[e];
        float diff = __fsub_rn(qv[cc], xv);
        out[e] = __fadd_rn(xv, diff);
        float s = __fmul_rn(diff, diff);
        for (int off = 32; off > 0; off >>= 1) s += __shfl_down(s, off, 64);
        sv[cc] = s;
    }
    if (lane == 0) {
        wsum[wid][0] = sv[0]; wsum[wid][1] = sv[1];
        wsum[wid][2] = sv[2]; wsum[wid][3] = sv[3];
    }
    __syncthreads();
    if (tid == 0) {
#pragma unroll
        for (int cc = 0; cc < 4; ++cc)
            bsum[(b << 11) + ((c0 + cc) << 3) + tc] =
                ((wsum[0][cc] + wsum[1][cc]) + (wsum[2][cc] + wsum[3][cc]));
    }
}

__global__ __launch_bounds__(1024) void finalize_kernel(const float* __restrict__ bsum,
                                                        float* __restrict__ out) {
    double s = 0.0;
    for (int i = threadIdx.x; i < 32768; i += 1024) s += (double)bsum[i];
    for (int off = 32; off > 0; off >>= 1) s += __shfl_down(s, off, 64);
    __shared__ double wsum[16];
    int lane = threadIdx.x & 63, wid = threadIdx.x >> 6;
    if (lane == 0) wsum[wid] = s;
    __syncthreads();
    if (threadIdx.x == 0) {
        double total = 0.0;
        for (int ww = 0; ww < 16; ++ww) total += wsum[ww];
        float mean = (float)(total / (double)NELEM);
        out[LOSS_OFF] = mean;
        out[LOSS_OFF + 1] = 0.25f * mean;
    }
}

extern "C" void kernel_launch(void* const* d_in, const int* in_sizes, int n_in,
                              void* d_out, int out_size, void* d_ws, size_t ws_size,
                              hipStream_t stream) {
    const float* x  = (const float*)d_in[0];
    const float* cb = (const float*)d_in[1];
    float* out = (float*)d_out;
    char* ws = (char*)d_ws;
    float* xsq = (float*)(ws + OFF_XSQ);
    float* esq = (float*)(ws + OFF_ESQ);
    unsigned long long* keys = (unsigned long long*)(ws + OFF_KEYS);
    float* bsum = (float*)(ws + OFF_BSUM);

    xsq_kernel<<<NROWS / 256, 256, 0, stream>>>(x, xsq);
    esq_kernel<<<KCODES / 256, 256, 0, stream>>>(cb, esq);

    if (ws_size >= WS_NEED) {
        __hip_bfloat16* Ehi = (__hip_bfloat16*)(ws + OFF_EHI);
        int* ccnt  = (int*)(ws + OFF_CCNT);
        int* clist = (int*)(ws + OFF_CLIST);
        split_e_kernel<<<(KCODES * DIM) / 1024, 256, 0, stream>>>(cb, Ehi);
        dist_cand_kernel<<<NROWS / 64, 256, 0, stream>>>(x, Ehi, esq, ccnt, clist);
        recheck_kernel<<<NROWS / 32, 256, 0, stream>>>(x, cb, xsq, esq, ccnt, clist, keys);
    } else {
        init_keys_kernel<<<NROWS / 256, 256, 0, stream>>>(keys);
        dist_kernel<<<(NROWS / 128) * (KCODES / 128), 256, 0, stream>>>(x, cb, xsq, esq, keys);
    }
    gather_kernel<<<(NB * 8 * 64), 256, 0, stream>>>(x, cb, keys, out, bsum);
    finalize_kernel<<<1, 1024, 0, stream>>>(bsum, out);
}

// Round 3
// 207.267 us; speedup vs baseline: 3.9071x; 3.9071x over previous
//
#include <hip/hip_runtime.h>
#include <hip/hip_bf16.h>

// Problem constants
#define KCODES 2048
#define DIM 256
#define TLEN 2048
#define NB 16
#define NROWS (NB * TLEN)          // 32768 rows (b*t)
#define NELEM (NB * DIM * TLEN)    // 8388608 elements of x / quant
#define LOSS_OFF NELEM
#define IDX_OFF (NELEM + 2)

// Approx filter margin (R8 analysis: requirement is s_approx(n*) - min_n s_approx(n)
// <= MARGIN, ~50-sigma safety for the single bf16 hi*hi sweep).
#define MARGIN 3e-3f

// Candidate list capacity per row. With retrospective (global-min) qualification
// E[#cands] ~ 5-15; overflow handled exactly by full-scan fallback in recheck.
#define CCAP 48

// ws layout (bytes) — total ~8.0 MB
#define OFF_XSQ   0ull                       // 131072 (fallback path only)
#define OFF_ESQ   131072ull                  // 8192
#define OFF_KEYS  139264ull                  // 262144
#define OFF_BSUM  401408ull                  // 131072
#define OFF_EHI   532480ull                  // 1048576
#define OFF_CCNT  1581056ull                 // 131072
#define OFF_CLIST 1712128ull                 // 32768*48*4 = 6291456
#define WS_NEED   8003584ull

typedef __bf16 bf16x8 __attribute__((ext_vector_type(8)));
typedef float  f32x4  __attribute__((ext_vector_type(4)));

__device__ __forceinline__ float sq_rn(float v) { return __fmul_rn(v, v); }

// order-preserving float<->u32 encoding (uint min == float min)
__device__ __forceinline__ unsigned encf(float f) {
    unsigned u = __float_as_uint(f);
    return (u & 0x80000000u) ? ~u : (u | 0x80000000u);
}
__device__ __forceinline__ float decf(unsigned k) {
    return __uint_as_float((k & 0x80000000u) ? (k & 0x7FFFFFFFu) : ~k);
}

// ---- x_sq: numpy pairwise sum (8-acc/128-block) — bit-exact vs np
// (fallback path only; main path computes xs inside recheck)
__global__ __launch_bounds__(256) void xsq_kernel(const float* __restrict__ x,
                                                  float* __restrict__ xsq) {
    int m = blockIdx.x * 256 + threadIdx.x;
    int b = m >> 11, t = m & (TLEN - 1);
    const float* p = x + (size_t)b * DIM * TLEN + t;
    float h[2];
#pragma unroll
    for (int half = 0; half < 2; ++half) {
        int c0 = half * 128;
        float r[8];
#pragma unroll
        for (int j = 0; j < 8; ++j) r[j] = sq_rn(p[(size_t)(c0 + j) * TLEN]);
        for (int i = 8; i < 128; i += 8) {
#pragma unroll
            for (int j = 0; j < 8; ++j)
                r[j] = __fadd_rn(r[j], sq_rn(p[(size_t)(c0 + i + j) * TLEN]));
        }
        h[half] = __fadd_rn(__fadd_rn(__fadd_rn(r[0], r[1]), __fadd_rn(r[2], r[3])),
                            __fadd_rn(__fadd_rn(r[4], r[5]), __fadd_rn(r[6], r[7])));
    }
    xsq[m] = __fadd_rn(h[0], h[1]);
}

__global__ __launch_bounds__(256) void esq_kernel(const float* __restrict__ cb,
                                                  float* __restrict__ esq) {
    int k = blockIdx.x * 256 + threadIdx.x;
    const float* p = cb + (size_t)k * DIM;
    float h[2];
#pragma unroll
    for (int half = 0; half < 2; ++half) {
        int c0 = half * 128;
        float r[8];
#pragma unroll
        for (int j = 0; j < 8; ++j) r[j] = sq_rn(p[c0 + j]);
        for (int i = 8; i < 128; i += 8) {
#pragma unroll
            for (int j = 0; j < 8; ++j)
                r[j] = __fadd_rn(r[j], sq_rn(p[c0 + i + j]));
        }
        h[half] = __fadd_rn(__fadd_rn(__fadd_rn(r[0], r[1]), __fadd_rn(r[2], r[3])),
                            __fadd_rn(__fadd_rn(r[4], r[5]), __fadd_rn(r[6], r[7])));
    }
    esq[k] = __fadd_rn(h[0], h[1]);
}

// ---- codebook [n][k] fp32 -> Ehi [n][k] bf16
__global__ __launch_bounds__(256) void split_e_kernel(const float* __restrict__ cb,
                                                      __hip_bfloat16* __restrict__ Ehi) {
    int i4 = (blockIdx.x * 256 + threadIdx.x) << 2;
    float4 v = *reinterpret_cast<const float4*>(cb + i4);
    alignas(8) __hip_bfloat16 h4[4];
    h4[0] = __float2bfloat16(v.x); h4[1] = __float2bfloat16(v.y);
    h4[2] = __float2bfloat16(v.z); h4[3] = __float2bfloat16(v.w);
    *reinterpret_cast<int2*>(Ehi + i4) = *reinterpret_cast<int2*>(h4);
}

// ---- stage one [128 codes][64 k] bf16 chunk of Ehi into LDS via global_load_lds,
// pre-swizzled-source XOR pattern (read side XORs (c&7)<<4). Wave w stages (and
// later reads) ONLY rows w*32..w*32+31 -> no cross-wave LDS hazards.
__device__ __forceinline__ void stage_chunk(const __hip_bfloat16* __restrict__ Ehi,
                                            __hip_bfloat16* dstbase,
                                            int s, int w, int srow, int scol) {
    int nt = s >> 2, kc = (s & 3) << 6;
    const __hip_bfloat16* gsrc =
        Ehi + (size_t)((nt << 7) + (w << 5) + srow) * DIM + kc + scol;
#pragma unroll
    for (int j = 0; j < 4; ++j)
        __builtin_amdgcn_global_load_lds(
            (const __attribute__((address_space(1))) unsigned int*)(gsrc + (size_t)(j << 3) * DIM),
            (__attribute__((address_space(3))) unsigned int*)(dstbase + (((w << 5) + (j << 3)) << 6)),
            16, 0, 0);
}

// ---- Phase A: 64 rows/block, loop over ALL 2048 codes. Barrier-free main loop
// (each wave reads only its own staged LDS rows), 2-buffer counted-vmcnt(4)
// pipeline with lgkmcnt(0) write-guard. During the loop each wave stores its
// per-32-code-subtile (min, mask) into exclusive LDS slots (no atomics). The
// post-loop expansion applies the RETROSPECTIVE global-min qualification
// (R1-proven superset logic): subtile qualifies iff wavemin <= gmin + MARGIN;
// bits were set iff s <= wavemin + MARGIN. Exactness: n* has s(n*) <= gmin + M,
// and wavemin >= gmin in its subtile -> bit set & subtile qualifies.
__global__ __launch_bounds__(256, 2) void dist_cand_kernel(const float* __restrict__ x,
                                                           const __hip_bfloat16* __restrict__ Ehi,
                                                           const float* __restrict__ esq,
                                                           int* __restrict__ ccnt_g,
                                                           int* __restrict__ clist_g) {
    __shared__ __hip_bfloat16 Bh[2][128 * 64];   // 32 KB, swizzled code tiles
    __shared__ float esq_s[KCODES];              // 8 KB
    __shared__ unsigned wmin_s[64][64];          // 16 KB [row][subtile] encoded min
    __shared__ unsigned mask_s[64][64];          // 16 KB [row][subtile] margin mask
    __shared__ int ccnt_s[64];

    int tid = threadIdx.x;
    int w = tid >> 6, lane = tid & 63;
    int q = lane >> 4, c = lane & 15;
    int swzc = (c & 7) << 4;
    int blk = blockIdx.x;                         // 512 blocks, 64 rows each
    int b = blk >> 5;
    int t0 = (blk << 6) & (TLEN - 1);
    const float* xb = x + (size_t)b * DIM * TLEN + t0;

    // esq -> LDS (epilogue reads become lgkm-only; keeps loop vmcnt clean)
#pragma unroll
    for (int i = 0; i < 8; ++i) esq_s[tid + i * 256] = esq[tid + i * 256];
    if (tid < 64) ccnt_s[tid] = 0;

    // A-frags: xf[mi][kh]: row t0 + mi*16 + c, k = kh*32 + q*8 + j
    bf16x8 xf[4][8];
#pragma unroll
    for (int mi = 0; mi < 4; ++mi) {
        int t = (mi << 4) + c;
#pragma unroll
        for (int kh = 0; kh < 8; ++kh) {
            alignas(16) __hip_bfloat16 h8[8];
#pragma unroll
            for (int j = 0; j < 8; ++j)
                h8[j] = __float2bfloat16(xb[(size_t)((kh << 5) + (q << 3) + j) * TLEN + t]);
            xf[mi][kh] = *reinterpret_cast<bf16x8*>(h8);
        }
    }

    f32x4 acc[2][4];
#pragma unroll
    for (int ci = 0; ci < 2; ++ci)
#pragma unroll
        for (int mi = 0; mi < 4; ++mi) acc[ci][mi] = (f32x4){0.f, 0.f, 0.f, 0.f};

    int srow = lane >> 3;
    int scol = ((lane & 7) ^ srow) << 3;

    // full drain (compiler emits vmcnt(0) lgkmcnt(0) before s_barrier): A-loads
    // and LDS inits settled -> in-loop vmcnt counts ONLY stage loads (4/chunk).
    __syncthreads();

    stage_chunk(Ehi, &Bh[0][0], 0, w, srow, scol);

    int cur = 0;
#pragma unroll 1
    for (int nt = 0; nt < 16; ++nt) {
#pragma unroll
        for (int kc = 0; kc < 4; ++kc) {
            int s = (nt << 2) + kc;
            // guard: my ds_reads from the buffer about to be overwritten are done
            asm volatile("s_waitcnt lgkmcnt(0)" ::: "memory");
            if (s < 63) stage_chunk(Ehi, &Bh[cur ^ 1][0], s + 1, w, srow, scol);
            if (s == 63) asm volatile("s_waitcnt vmcnt(0)" ::: "memory");
            else         asm volatile("s_waitcnt vmcnt(4)" ::: "memory");

            const char* basep = reinterpret_cast<const char*>(&Bh[cur][0]);
#pragma unroll
            for (int kh = 0; kh < 2; ++kh) {
                int swz = ((kh << 6) | (q << 4)) ^ swzc;
                bf16x8 cf0 = *reinterpret_cast<const bf16x8*>(basep + ((((w << 5) + c) << 7) + swz));
                bf16x8 cf1 = *reinterpret_cast<const bf16x8*>(basep + ((((w << 5) + 16 + c) << 7) + swz));
#pragma unroll
                for (int mi = 0; mi < 4; ++mi) {
                    acc[0][mi] = __builtin_amdgcn_mfma_f32_16x16x32_bf16(cf0, xf[mi][(kc << 1) | kh], acc[0][mi], 0, 0, 0);
                    acc[1][mi] = __builtin_amdgcn_mfma_f32_16x16x32_bf16(cf1, xf[mi][(kc << 1) | kh], acc[1][mi], 0, 0, 0);
                }
            }
            cur ^= 1;
        }

        // per-nt epilogue: s = esq - 2*acc (row-constant xsq cancels in all
        // comparisons). Store per-wave-subtile (min, mask) — exclusive slots.
        float ev[8];
#pragma unroll
        for (int ci = 0; ci < 2; ++ci)
#pragma unroll
            for (int reg = 0; reg < 4; ++reg)
                ev[ci * 4 + reg] = esq_s[(nt << 7) + (w << 5) + (ci << 4) + (q << 2) + reg];

#pragma unroll
        for (int mi = 0; mi < 4; ++mi) {
            int r = (mi << 4) + c;
            float s8[8];
#pragma unroll
            for (int ci = 0; ci < 2; ++ci)
#pragma unroll
                for (int reg = 0; reg < 4; ++reg)
                    s8[ci * 4 + reg] = fmaf(-2.0f, acc[ci][mi][reg], ev[ci * 4 + reg]);
            float t01 = fminf(fminf(s8[0], s8[1]), fminf(s8[2], s8[3]));
            float t23 = fminf(fminf(s8[4], s8[5]), fminf(s8[6], s8[7]));
            float wmin = fminf(t01, t23);
            wmin = fminf(wmin, __shfl_xor(wmin, 16, 64));
            wmin = fminf(wmin, __shfl_xor(wmin, 32, 64));
            float thrw = wmin + MARGIN;
            unsigned bits = 0;
#pragma unroll
            for (int v = 0; v < 8; ++v)
                if (s8[v] <= thrw)
                    bits |= 1u << (((v >> 2) << 4) | (q << 2) | (v & 3));
            bits |= (unsigned)__shfl_xor((int)bits, 16, 64);
            bits |= (unsigned)__shfl_xor((int)bits, 32, 64);
            if (q == 0) {
                int st = (nt << 2) | w;
                wmin_s[r][st] = encf(wmin);
                mask_s[r][st] = bits;
            }
            acc[0][mi] = (f32x4){0.f, 0.f, 0.f, 0.f};
            acc[1][mi] = (f32x4){0.f, 0.f, 0.f, 0.f};
        }
    }

    __syncthreads();

    // Expansion: retrospective global-min qualification, then compact lists.
    {
        int r = tid >> 2, j4 = tid & 3;
        int m = (blk << 6) + r;
        unsigned ge = 0xFFFFFFFFu;
#pragma unroll
        for (int i = 0; i < 16; ++i) ge = min(ge, wmin_s[r][(i << 2) | j4]);
        ge = min(ge, (unsigned)__shfl_xor((int)ge, 1, 4));
        ge = min(ge, (unsigned)__shfl_xor((int)ge, 2, 4));
        float thr = decf(ge) + MARGIN;
        for (int st = j4; st < 64; st += 4) {
            if (decf(wmin_s[r][st]) <= thr) {
                unsigned bits = mask_s[r][st];
                while (bits) {
                    int bpos = __ffs(bits) - 1; bits &= bits - 1;
                    int pos = atomicAdd(&ccnt_s[r], 1);
                    if (pos < CCAP) clist_g[(size_t)m * CCAP + pos] = (st << 5) + bpos;
                }
            }
        }
    }
    __syncthreads();
    if ((tid & 3) == 0) ccnt_g[(blk << 6) + (tid >> 2)] = ccnt_s[tid >> 2];
}

// ---- Phase B: exact recheck over candidate lists. xs computed internally from
// the staged xT tile with the EXACT np pairwise chain (r[j] strided accumulators
// + xor-shfl tree reproduces ((r0+r1)+(r2+r3))+((r4+r5)+(r6+r7)) bit-exactly).
// Full-scan fallback on overflow keeps exactness unconditional.
__global__ __launch_bounds__(256) void recheck_kernel(const float* __restrict__ x,
                                                      const float* __restrict__ cb,
                                                      const float* __restrict__ esq,
                                                      const int* __restrict__ ccnt,
                                                      const int* __restrict__ clist,
                                                      unsigned long long* __restrict__ keys) {
    __shared__ float xT[DIM * 33];

    int tid = threadIdx.x;
    int blk = blockIdx.x;               // 1024 blocks, 32 rows each
    int b = blk >> 6, t0 = (blk & 63) << 5;
    const float* xb = x + (size_t)b * DIM * TLEN + t0;

    {   // coalesced staging: 8 c-rows x 32 t per iter
        int tl = tid & 31, c8 = tid >> 5;
        for (int cc = 0; cc < 32; ++cc) {
            int c = (cc << 3) + c8;
            xT[c * 33 + tl] = xb[(size_t)c * TLEN + tl];
        }
    }
    __syncthreads();

    int g = tid >> 3, l3 = tid & 7;     // group g handles row t0+g
    int m = (b << 11) + t0 + g;

    // xs: np pairwise chain, bit-exact (lane l3 owns accumulator r[l3])
    float h[2];
#pragma unroll
    for (int half = 0; half < 2; ++half) {
        int c0 = half * 128;
        float r = sq_rn(xT[(c0 + l3) * 33 + g]);
        for (int i = 8; i < 128; i += 8)
            r = __fadd_rn(r, sq_rn(xT[(c0 + i + l3) * 33 + g]));
        float a = __fadd_rn(r, __shfl_xor(r, 1, 8));
        float bb = __fadd_rn(a, __shfl_xor(a, 2, 8));
        h[half] = __fadd_rn(bb, __shfl_xor(bb, 4, 8));
    }
    float xs = __fadd_rn(h[0], h[1]);

    int cnt = ccnt[m];
    float bd = 3.4e38f; int bi = 0x7fffffff;

    if (cnt <= CCAP) {
        for (int j = l3; j < cnt; j += 8) {
            int n = clist[(size_t)m * CCAP + j];
            const float* crow = cb + (size_t)n * DIM;
            float d = 0.f;
            for (int k = 0; k < DIM; k += 4) {     // ascending-k fmaf chain == np mm
                float4 cv = *reinterpret_cast<const float4*>(crow + k);
                d = fmaf(xT[(k + 0) * 33 + g], cv.x, d);
                d = fmaf(xT[(k + 1) * 33 + g], cv.y, d);
                d = fmaf(xT[(k + 2) * 33 + g], cv.z, d);
                d = fmaf(xT[(k + 3) * 33 + g], cv.w, d);
            }
            float d2 = __fadd_rn(__fadd_rn(xs, -2.0f * d), esq[n]);
            if (d2 < bd || (d2 == bd && n < bi)) { bd = d2; bi = n; }
        }
    } else {
        // overflow fallback: exact full scan (same formula, any order is fine)
        for (int n = l3; n < KCODES; n += 8) {
            const float* crow = cb + (size_t)n * DIM;
            float d = 0.f;
            for (int k = 0; k < DIM; k += 4) {
                float4 cv = *reinterpret_cast<const float4*>(crow + k);
                d = fmaf(xT[(k + 0) * 33 + g], cv.x, d);
                d = fmaf(xT[(k + 1) * 33 + g], cv.y, d);
                d = fmaf(xT[(k + 2) * 33 + g], cv.z, d);
                d = fmaf(xT[(k + 3) * 33 + g], cv.w, d);
            }
            float d2 = __fadd_rn(__fadd_rn(xs, -2.0f * d), esq[n]);
            if (d2 < bd || (d2 == bd && n < bi)) { bd = d2; bi = n; }
        }
    }
    for (int off = 1; off < 8; off <<= 1) {
        float od = __shfl_xor(bd, off, 8);
        int   oi = __shfl_xor(bi, off, 8);
        if (od < bd || (od == bd && oi < bi)) { bd = od; bi = oi; }
    }
    if (l3 == 0)
        keys[m] = ((unsigned long long)__float_as_uint(bd) << 32) | (unsigned)(bi & 2047);
}

// ======== fallback path (R5): used only if ws_size is too small ========
__global__ __launch_bounds__(256) void init_keys_kernel(unsigned long long* __restrict__ keys) {
    keys[blockIdx.x * 256 + threadIdx.x] = ~0ULL;
}

__global__ __launch_bounds__(256, 4) void dist_kernel(const float* __restrict__ x,
                                                      const float* __restrict__ cb,
                                                      const float* __restrict__ xsq,
                                                      const float* __restrict__ esq,
                                                      unsigned long long* __restrict__ keys) {
    __shared__ float As[16][128];
    __shared__ float Bs[16][132];
    int blk = blockIdx.x;
    int nt = blk & 15, mt = blk >> 4;
    int m0 = mt << 7;
    int b = m0 >> 11, t0 = m0 & (TLEN - 1);
    int n0 = nt << 7;
    int tid = threadIdx.x;
    int tm = tid >> 4, tn = tid & 15;
    const float* xbase = x + (size_t)b * DIM * TLEN + t0;
    float acc[8][8] = {};
    for (int kk = 0; kk < DIM; kk += 16) {
#pragma unroll
        for (int h = 0; h < 2; ++h) {
            int qq = tid + (h << 8);
            int k = qq >> 5, mq = (qq & 31) << 2;
            float4 v = *reinterpret_cast<const float4*>(xbase + (size_t)(kk + k) * TLEN + mq);
            *reinterpret_cast<float4*>(&As[k][mq]) = v;
        }
#pragma unroll
        for (int h = 0; h < 2; ++h) {
            int qq = tid + (h << 8);
            int nr = qq >> 2, kc = (qq & 3) << 2;
            float4 v = *reinterpret_cast<const float4*>(cb + (size_t)(n0 + nr) * DIM + kk + kc);
            Bs[kc + 0][nr] = v.x; Bs[kc + 1][nr] = v.y;
            Bs[kc + 2][nr] = v.z; Bs[kc + 3][nr] = v.w;
        }
        __syncthreads();
#pragma unroll
        for (int k = 0; k < 16; ++k) {
            float4 a0 = *reinterpret_cast<const float4*>(&As[k][tm << 2]);
            float4 a1 = *reinterpret_cast<const float4*>(&As[k][64 + (tm << 2)]);
            float4 b0 = *reinterpret_cast<const float4*>(&Bs[k][tn << 2]);
            float4 b1 = *reinterpret_cast<const float4*>(&Bs[k][64 + (tn << 2)]);
            float am[8] = {a0.x, a0.y, a0.z, a0.w, a1.x, a1.y, a1.z, a1.w};
            float bn[8] = {b0.x, b0.y, b0.z, b0.w, b1.x, b1.y, b1.z, b1.w};
#pragma unroll
            for (int mi = 0; mi < 8; ++mi)
#pragma unroll
                for (int ni = 0; ni < 8; ++ni)
                    acc[mi][ni] = fmaf(am[mi], bn[ni], acc[mi][ni]);
        }
        __syncthreads();
    }
    int cn[8]; float es[8];
#pragma unroll
    for (int ni = 0; ni < 8; ++ni) {
        cn[ni] = n0 + ((ni < 4) ? (tn << 2) + ni : 60 + (tn << 2) + ni);
        es[ni] = esq[cn[ni]];
    }
#pragma unroll
    for (int mi = 0; mi < 8; ++mi) {
        int m = m0 + ((mi < 4) ? (tm << 2) + mi : 60 + (tm << 2) + mi);
        float xs = xsq[m];
        float bd = 3.4e38f;
        int bi = 0x7fffffff;
#pragma unroll
        for (int ni = 0; ni < 8; ++ni) {
            float d2 = __fadd_rn(__fadd_rn(xs, -2.0f * acc[mi][ni]), es[ni]);
            if (d2 < bd) { bd = d2; bi = cn[ni]; }
        }
        for (int off = 1; off < 16; off <<= 1) {
            float od = __shfl_xor(bd, off, 16);
            int oi = __shfl_xor(bi, off, 16);
            if (od < bd || (od == bd && oi < bi)) { bd = od; bi = oi; }
        }
        if (tn == 0) {
            unsigned long long key =
                ((unsigned long long)__float_as_uint(bd) << 32) | (unsigned)(bi & 2047);
            atomicMin(&keys[m], key);
        }
    }
}
// ======== end fallback ========

// ---- gather + STE output + idx + per-block loss sums (c-quad float4 gather)
__global__ __launch_bounds__(256) void gather_kernel(const float* __restrict__ x,
                                                     const float* __restrict__ cb,
                                                     const unsigned long long* __restrict__ keys,
                                                     float* __restrict__ out,
                                                     float* __restrict__ bsum) {
    int tid = threadIdx.x;
    int blk = blockIdx.x;               // 8192 = 16 b x 8 tc x 64 c4
    int c4 = blk & 63, tc = (blk >> 6) & 7, b = blk >> 9;
    int c0 = c4 << 2;
    int t = (tc << 8) + tid;
    int m = (b << 11) + t;
    unsigned idx = (unsigned)(keys[m]) & 2047u;
    float4 cv = *reinterpret_cast<const float4*>(cb + (size_t)idx * DIM + c0);
    if (c4 == 0) out[(size_t)IDX_OFF + m] = (float)idx;

    float qv[4] = {cv.x, cv.y, cv.z, cv.w};
    __shared__ float wsum[4][4];
    int lane = tid & 63, wid = tid >> 6;
    float sv[4];
#pragma unroll
    for (int cc = 0; cc < 4; ++cc) {
        size_t e = (size_t)b * (DIM * TLEN) + (size_t)(c0 + cc) * TLEN + t;
        float xv = x[e];
        float diff = __fsub_rn(qv[cc], xv);
        out[e] = __fadd_rn(xv, diff);
        float s = __fmul_rn(diff, diff);
        for (int off = 32; off > 0; off >>= 1) s += __shfl_down(s, off, 64);
        sv[cc] = s;
    }
    if (lane == 0) {
        wsum[wid][0] = sv[0]; wsum[wid][1] = sv[1];
        wsum[wid][2] = sv[2]; wsum[wid][3] = sv[3];
    }
    __syncthreads();
    if (tid == 0) {
#pragma unroll
        for (int cc = 0; cc < 4; ++cc)
            bsum[(b << 11) + ((c0 + cc) << 3) + tc] =
                ((wsum[0][cc] + wsum[1][cc]) + (wsum[2][cc] + wsum[3][cc]));
    }
}

__global__ __launch_bounds__(1024) void finalize_kernel(const float* __restrict__ bsum,
                                                        float* __restrict__ out) {
    double s = 0.0;
    for (int i = threadIdx.x; i < 32768; i += 1024) s += (double)bsum[i];
    for (int off = 32; off > 0; off >>= 1) s += __shfl_down(s, off, 64);
    __shared__ double wsum[16];
    int lane = threadIdx.x & 63, wid = threadIdx.x >> 6;
    if (lane == 0) wsum[wid] = s;
    __syncthreads();
    if (threadIdx.x == 0) {
        double total = 0.0;
        for (int ww = 0; ww < 16; ++ww) total += wsum[ww];
        float mean = (float)(total / (double)NELEM);
        out[LOSS_OFF] = mean;
        out[LOSS_OFF + 1] = 0.25f * mean;
    }
}

extern "C" void kernel_launch(void* const* d_in, const int* in_sizes, int n_in,
                              void* d_out, int out_size, void* d_ws, size_t ws_size,
                              hipStream_t stream) {
    const float* x  = (const float*)d_in[0];
    const float* cb = (const float*)d_in[1];
    float* out = (float*)d_out;
    char* ws = (char*)d_ws;
    float* xsq = (float*)(ws + OFF_XSQ);
    float* esq = (float*)(ws + OFF_ESQ);
    unsigned long long* keys = (unsigned long long*)(ws + OFF_KEYS);
    float* bsum = (float*)(ws + OFF_BSUM);

    esq_kernel<<<KCODES / 256, 256, 0, stream>>>(cb, esq);

    if (ws_size >= WS_NEED) {
        __hip_bfloat16* Ehi = (__hip_bfloat16*)(ws + OFF_EHI);
        int* ccnt  = (int*)(ws + OFF_CCNT);
        int* clist = (int*)(ws + OFF_CLIST);
        split_e_kernel<<<(KCODES * DIM) / 1024, 256, 0, stream>>>(cb, Ehi);
        dist_cand_kernel<<<NROWS / 64, 256, 0, stream>>>(x, Ehi, esq, ccnt, clist);
        recheck_kernel<<<NROWS / 32, 256, 0, stream>>>(x, cb, esq, ccnt, clist, keys);
    } else {
        xsq_kernel<<<NROWS / 256, 256, 0, stream>>>(x, xsq);
        init_keys_kernel<<<NROWS / 256, 256, 0, stream>>>(keys);
        dist_kernel<<<(NROWS / 128) * (KCODES / 128), 256, 0, stream>>>(x, cb, xsq, esq, keys);
    }
    gather_kernel<<<(NB * 8 * 64), 256, 0, stream>>>(x, cb, keys, out, bsum);
    finalize_kernel<<<1, 1024, 0, stream>>>(bsum, out);
}